// Round 2
// baseline (284.889 us; speedup 1.0000x reference)
//
#include <hip/hip_runtime.h>

// Problem constants (match the reference)
#define Bv 32
#define Sv 1024
#define Hv 1024
#define Vv 250002

#define GRID  1024          // 4 blocks/CU x 256 CUs -> all co-resident
#define BLOCK 256           // 4 waves/block
#define ROWS_PER_BLOCK 32   // 32768 rows / 1024 blocks
#define ROWS_PER_WAVE  8

// Monotone barrier counter (module-scope, zero-init at load). Each launch adds
// exactly GRID, so it is always a multiple of GRID at call boundaries; the
// barrier target is the next multiple of GRID -> no reset, no cross-call state
// dependence in the OUTPUT (counter only orders work within one launch).
__device__ unsigned g_barrier = 0;

// Fused: zero out[B,V] + per-row dot(hidden,W)+bias+ReLU + scatter-max.
// Phase Z (zero slice) and Phase D (dots) touch disjoint data vs other blocks'
// scatters, so they run pre-barrier; Phase S (atomicMax into out) runs only
// after ALL blocks passed the barrier (i.e., out is fully zeroed).
// atomicMax on int bit-pattern is exact for non-negative floats vs a zeroed
// table. Skipping ids<4 == reference's final set(0.0) on columns {0..3}.
__global__ __launch_bounds__(BLOCK, 4) void fused_kernel(
        const float* __restrict__ hidden,   // [B*S, H]
        const int*   __restrict__ ids,      // [B*S]
        const float* __restrict__ W,        // [H]
        const float* __restrict__ bias,     // [1]
        float*       __restrict__ out)      // [B, V]
{
    const int tid  = threadIdx.x;
    const int lane = tid & 63;
    const int wave = tid >> 6;

    // --- W into registers (4 KB; reused across 8 rows per wave) ---
    const float4* wp = reinterpret_cast<const float4*>(W);
    const float4 w0 = wp[lane];
    const float4 w1 = wp[lane + 64];
    const float4 w2 = wp[lane + 128];
    const float4 w3 = wp[lane + 192];

    // --- Phase Z: zero this block's share of out (float4, grid-stride) ---
    float4* out4 = reinterpret_cast<float4*>(out);
    const int n4 = (Bv * Vv) / 4;  // 2,000,016
    for (int i = blockIdx.x * BLOCK + tid; i < n4; i += GRID * BLOCK)
        out4[i] = make_float4(0.f, 0.f, 0.f, 0.f);

    // --- Phase D: 8 rows per wave, dot + butterfly reduce (all lanes get sum) ---
    const int rowBase = blockIdx.x * ROWS_PER_BLOCK + wave * ROWS_PER_WAVE;
    float tw[ROWS_PER_WAVE];
#pragma unroll
    for (int r = 0; r < ROWS_PER_WAVE; ++r) {
        const float4* hp =
            reinterpret_cast<const float4*>(hidden + (size_t)(rowBase + r) * Hv);
        const float4 h0 = hp[lane];
        const float4 h1 = hp[lane + 64];
        const float4 h2 = hp[lane + 128];
        const float4 h3 = hp[lane + 192];
        float acc = h0.x * w0.x + h0.y * w0.y + h0.z * w0.z + h0.w * w0.w;
        acc      += h1.x * w1.x + h1.y * w1.y + h1.z * w1.z + h1.w * w1.w;
        acc      += h2.x * w2.x + h2.y * w2.y + h2.z * w2.z + h2.w * w2.w;
        acc      += h3.x * w3.x + h3.y * w3.y + h3.z * w3.z + h3.w * w3.w;
#pragma unroll
        for (int off = 32; off >= 1; off >>= 1)
            acc += __shfl_xor(acc, off, 64);
        tw[r] = acc;   // every lane holds the row sum
    }

    // --- Device-wide barrier: all zero-stores visible before any scatter ---
    __threadfence();          // make this block's zero-stores visible
    __syncthreads();          // all waves in block done with Z (and D)
    if (tid == 0) {
        unsigned old = atomicAdd(&g_barrier, 1u);          // device scope
        unsigned target = old - (old % GRID) + GRID;       // next multiple
        while ((int)(__hip_atomic_load(&g_barrier, __ATOMIC_RELAXED,
                                       __HIP_MEMORY_SCOPE_AGENT) - target) < 0) {
            __builtin_amdgcn_s_sleep(1);
        }
    }
    __syncthreads();
    __threadfence();          // acquire side

    // --- Phase S: lanes 0..7 scatter their wave's 8 rows ---
    // Static-select tw[lane] without runtime register indexing (no scratch).
    float myt = tw[0];
#pragma unroll
    for (int r = 1; r < ROWS_PER_WAVE; ++r)
        myt = (lane == r) ? tw[r] : myt;

    if (lane < ROWS_PER_WAVE) {
        const float t = myt + bias[0];
        if (t > 0.f) {
            const int row = rowBase + lane;
            const int id  = ids[row];
            if (id >= 4) {
                const int b = row >> 10;   // S = 1024
                atomicMax(reinterpret_cast<int*>(out + (size_t)b * Vv + id),
                          __float_as_int(t));
            }
        }
    }
}

extern "C" void kernel_launch(void* const* d_in, const int* in_sizes, int n_in,
                              void* d_out, int out_size, void* d_ws, size_t ws_size,
                              hipStream_t stream) {
    const float* hidden = (const float*)d_in[0];   // [B, S, H] fp32
    const int*   ids    = (const int*)  d_in[1];   // [B, S] int32
    const float* W      = (const float*)d_in[2];   // [1, H] fp32
    const float* bias   = (const float*)d_in[3];   // [1] fp32
    float*       out    = (float*)d_out;           // [B, V] fp32

    fused_kernel<<<GRID, BLOCK, 0, stream>>>(hidden, ids, W, bias, out);
}

// Round 3
// 32.478 us; speedup vs baseline: 8.7718x; 8.7718x over previous
//
#include <hip/hip_runtime.h>

// Problem constants (match the reference)
#define Bv 32
#define Sv 1024
#define Hv 1024
#define Vv 250002

#define ZERO_BLOCKS 2048
#define DOT_BLOCKS  8192          // 4 waves/block, 1 row per wave -> 32768 rows
#define K1_GRID     (ZERO_BLOCKS + DOT_BLOCKS)

// ---------------------------------------------------------------------------
// K1: two block roles in one dispatch (overlap zero-writes with row reads).
//   blocks [0, ZERO_BLOCKS)          : zero out[B,V] (float4 grid-stride)
//   blocks [ZERO_BLOCKS, K1_GRID)    : one (b,s) row per wave:
//       t = relu(dot(hidden[row,:], W) + bias);  tw[row] = t
// No inter-block dependency inside K1: scatter happens in K2 (stream-ordered).
// ---------------------------------------------------------------------------
__global__ __launch_bounds__(256) void k1_zero_dot(
        const float* __restrict__ hidden,   // [B*S, H]
        const float* __restrict__ W,        // [H]
        const float* __restrict__ bias,     // [1]
        float*       __restrict__ out,      // [B, V]
        float*       __restrict__ tw)       // [B*S] (workspace)
{
    const int bid = blockIdx.x;
    const int tid = threadIdx.x;

    if (bid < ZERO_BLOCKS) {
        float4* out4 = reinterpret_cast<float4*>(out);
        const int n4 = (Bv * Vv) / 4;  // 2,000,016
        for (int i = bid * 256 + tid; i < n4; i += ZERO_BLOCKS * 256)
            out4[i] = make_float4(0.f, 0.f, 0.f, 0.f);
        return;
    }

    const int lane = tid & 63;
    const int wave = tid >> 6;
    const int row  = (bid - ZERO_BLOCKS) * 4 + wave;   // [0, 32768)

    const float4* hp = reinterpret_cast<const float4*>(hidden + (size_t)row * Hv);
    const float4* wp = reinterpret_cast<const float4*>(W);

    const float4 h0 = hp[lane];
    const float4 h1 = hp[lane + 64];
    const float4 h2 = hp[lane + 128];
    const float4 h3 = hp[lane + 192];
    const float4 w0 = wp[lane];
    const float4 w1 = wp[lane + 64];
    const float4 w2 = wp[lane + 128];
    const float4 w3 = wp[lane + 192];

    float acc = h0.x * w0.x + h0.y * w0.y + h0.z * w0.z + h0.w * w0.w;
    acc      += h1.x * w1.x + h1.y * w1.y + h1.z * w1.z + h1.w * w1.w;
    acc      += h2.x * w2.x + h2.y * w2.y + h2.z * w2.z + h2.w * w2.w;
    acc      += h3.x * w3.x + h3.y * w3.y + h3.z * w3.z + h3.w * w3.w;

#pragma unroll
    for (int off = 32; off >= 1; off >>= 1)
        acc += __shfl_xor(acc, off, 64);

    if (lane == 0)
        tw[row] = fmaxf(acc + bias[0], 0.f);
}

// ---------------------------------------------------------------------------
// K2: scatter-max. atomicMax on the int bit pattern is exact for non-negative
// floats vs a zero-initialized table; skipping ids<4 == reference's final
// set(0.0) on columns {0,1,2,3}.
// ---------------------------------------------------------------------------
__global__ __launch_bounds__(256) void k2_scatter(
        const float* __restrict__ tw,       // [B*S]
        const int*   __restrict__ ids,      // [B*S]
        float*       __restrict__ out)      // [B, V]
{
    const int i = blockIdx.x * 256 + threadIdx.x;   // [0, 32768)
    const float t = tw[i];
    if (t > 0.f) {
        const int id = ids[i];
        if (id >= 4) {
            const int b = i >> 10;   // S = 1024
            atomicMax(reinterpret_cast<int*>(out + (size_t)b * Vv + id),
                      __float_as_int(t));
        }
    }
}

extern "C" void kernel_launch(void* const* d_in, const int* in_sizes, int n_in,
                              void* d_out, int out_size, void* d_ws, size_t ws_size,
                              hipStream_t stream) {
    const float* hidden = (const float*)d_in[0];   // [B, S, H] fp32
    const int*   ids    = (const int*)  d_in[1];   // [B, S] int32
    const float* W      = (const float*)d_in[2];   // [1, H] fp32
    const float* bias   = (const float*)d_in[3];   // [1] fp32
    float*       out    = (float*)d_out;           // [B, V] fp32
    float*       tw     = (float*)d_ws;            // [B*S] = 128 KB scratch

    k1_zero_dot<<<K1_GRID, 256, 0, stream>>>(hidden, W, bias, out, tw);
    k2_scatter<<<(Bv * Sv) / 256, 256, 0, stream>>>(tw, ids, out);
}

// Round 5
// 29.854 us; speedup vs baseline: 9.5429x; 1.0879x over previous
//
#include <hip/hip_runtime.h>

// Problem constants (match the reference)
#define Bv 32
#define Sv 1024
#define Hv 1024
#define Vv 250002

#define K1_GRID 8192     // 4 waves/block, 1 row per wave -> 32768 rows
#define BLOCK   256

typedef float f4_t __attribute__((ext_vector_type(4)));   // native vec for nontemporal

// ---------------------------------------------------------------------------
// K1: every block does BOTH roles so zero-writes overlap row-reads in the
// memory system (the two-role-grid version ran them as sequential phases):
//   1) fire-and-forget: zero a 4 KB slice of out[B,V] (nontemporal float4,
//      one store per thread; 8192*256 = 2,097,152 >= 2,000,016 slots)
//   2) stream: each wave reads one 4 KB hidden row (4 x float4/lane,
//      coalesced), dot with W (register-held, L1-resident), butterfly
//      reduce, lane 0 writes relu(dot+bias) to tw[row] in d_ws.
// Scatter is deferred to K2 (needs all zeroing complete; stream-ordered).
// ---------------------------------------------------------------------------
__global__ __launch_bounds__(BLOCK) void k1_zero_dot(
        const float* __restrict__ hidden,   // [B*S, H]
        const float* __restrict__ W,        // [H]
        const float* __restrict__ bias,     // [1]
        float*       __restrict__ out,      // [B, V]
        float*       __restrict__ tw)       // [B*S] (workspace)
{
    const int bid  = blockIdx.x;
    const int tid  = threadIdx.x;
    const int lane = tid & 63;
    const int wave = tid >> 6;

    // --- role 1: zero slice (no wait; overlaps everything below) ---
    {
        f4_t* out4 = reinterpret_cast<f4_t*>(out);
        const int n4 = (Bv * Vv) / 4;          // 2,000,016
        const int i  = bid * BLOCK + tid;
        if (i < n4) {
            f4_t z = {0.f, 0.f, 0.f, 0.f};
            __builtin_nontemporal_store(z, &out4[i]);
        }
    }

    // --- role 2: one (b,s) row per wave ---
    const int row = bid * 4 + wave;            // [0, 32768)

    const float4* hp = reinterpret_cast<const float4*>(hidden + (size_t)row * Hv);
    const float4* wp = reinterpret_cast<const float4*>(W);

    const float4 h0 = hp[lane];
    const float4 h1 = hp[lane + 64];
    const float4 h2 = hp[lane + 128];
    const float4 h3 = hp[lane + 192];
    const float4 w0 = wp[lane];
    const float4 w1 = wp[lane + 64];
    const float4 w2 = wp[lane + 128];
    const float4 w3 = wp[lane + 192];

    float acc = h0.x * w0.x + h0.y * w0.y + h0.z * w0.z + h0.w * w0.w;
    acc      += h1.x * w1.x + h1.y * w1.y + h1.z * w1.z + h1.w * w1.w;
    acc      += h2.x * w2.x + h2.y * w2.y + h2.z * w2.z + h2.w * w2.w;
    acc      += h3.x * w3.x + h3.y * w3.y + h3.z * w3.z + h3.w * w3.w;

#pragma unroll
    for (int off = 32; off >= 1; off >>= 1)
        acc += __shfl_xor(acc, off, 64);

    if (lane == 0)
        tw[row] = fmaxf(acc + bias[0], 0.f);
}

// ---------------------------------------------------------------------------
// K2: scatter-max. atomicMax on the int bit pattern is exact for non-negative
// floats vs a zero-initialized table; skipping ids<4 == reference's final
// set(0.0) on columns {0,1,2,3}.
// ---------------------------------------------------------------------------
__global__ __launch_bounds__(256) void k2_scatter(
        const float* __restrict__ tw,       // [B*S]
        const int*   __restrict__ ids,      // [B*S]
        float*       __restrict__ out)      // [B, V]
{
    const int i = blockIdx.x * 256 + threadIdx.x;   // [0, 32768)
    const float t = tw[i];
    if (t > 0.f) {
        const int id = ids[i];
        if (id >= 4) {
            const int b = i >> 10;   // S = 1024
            atomicMax(reinterpret_cast<int*>(out + (size_t)b * Vv + id),
                      __float_as_int(t));
        }
    }
}

extern "C" void kernel_launch(void* const* d_in, const int* in_sizes, int n_in,
                              void* d_out, int out_size, void* d_ws, size_t ws_size,
                              hipStream_t stream) {
    const float* hidden = (const float*)d_in[0];   // [B, S, H] fp32
    const int*   ids    = (const int*)  d_in[1];   // [B, S] int32
    const float* W      = (const float*)d_in[2];   // [1, H] fp32
    const float* bias   = (const float*)d_in[3];   // [1] fp32
    float*       out    = (float*)d_out;           // [B, V] fp32
    float*       tw     = (float*)d_ws;            // [B*S] = 128 KB scratch

    k1_zero_dot<<<K1_GRID, BLOCK, 0, stream>>>(hidden, W, bias, out, tw);
    k2_scatter<<<(Bv * Sv) / 256, 256, 0, stream>>>(tw, ids, out);
}